// Round 2
// baseline (1069.685 us; speedup 1.0000x reference)
//
#include <hip/hip_runtime.h>
#include <stdint.h>
#include <math.h>

typedef unsigned short u16;
typedef unsigned int u32;

#define HID   768
#define TGT   20
#define LBL   30522
#define RPAIR 512
#define ROWS  10240          // RPAIR * TGT
#define KCAT  1536           // 2*HID (lh|rh)
#define NPAD  30592          // 239 * 128  (LBL padded to tile multiple)

typedef float  f32x4  __attribute__((ext_vector_type(4)));
typedef __bf16 bf16x8 __attribute__((ext_vector_type(8)));

__device__ __forceinline__ u16 f2bf(float f) {
  u32 u = __float_as_uint(f);
  u += 0x7fffu + ((u >> 16) & 1u);          // RNE
  return (u16)(u >> 16);
}
__device__ __forceinline__ float bf2f(u16 h) {
  return __uint_as_float(((u32)h) << 16);
}
__device__ __forceinline__ float gelu_tanh(float x) {
  float x3 = x * x * x;
  float t = tanhf(0.7978845608028654f * (x + 0.044715f * x3));
  return 0.5f * x * (1.0f + t);
}

// async global->LDS, 16B per lane; lds dst must be wave-uniform base (HW adds lane*16)
__device__ __forceinline__ void async16(u16* lds, const u16* g) {
  __builtin_amdgcn_global_load_lds(
      (__attribute__((address_space(1))) void*)const_cast<u16*>(g),
      (__attribute__((address_space(3))) void*)lds,
      16, 0, 0);
}

// ---------------------------------------------------------------------------
// Transpose + f32->bf16 convert:  B[K][N] f32  ->  Bt[Npad][K] bf16 (pad rows zeroed)
// ---------------------------------------------------------------------------
__global__ __launch_bounds__(256) void tconv_kernel(const float* __restrict__ B,
                                                    u16* __restrict__ Bt,
                                                    int K, int N, int Npad) {
  __shared__ u16 tile[32][34];
  int n0 = blockIdx.x * 32, k0 = blockIdx.y * 32;
  int tx = threadIdx.x & 31, ty = threadIdx.x >> 5;   // ty: 0..7
#pragma unroll
  for (int i = 0; i < 4; i++) {
    int kk = ty + i * 8;
    int k = k0 + kk, n = n0 + tx;
    float v = (k < K && n < N) ? B[(size_t)k * N + n] : 0.0f;
    tile[kk][tx] = f2bf(v);
  }
  __syncthreads();
#pragma unroll
  for (int i = 0; i < 4; i++) {
    int nn = ty + i * 8;
    int n = n0 + nn, k = k0 + tx;
    if (n < Npad && k < K) Bt[(size_t)n * K + k] = tile[tx][nn];
  }
}

// ---------------------------------------------------------------------------
// Gather pair rows -> A1[512][1536] bf16   (lh | rh), handles int32 or int64 pairs
// ---------------------------------------------------------------------------
__global__ __launch_bounds__(256) void gather_kernel(const float* __restrict__ nodes,
                                                     const int* __restrict__ p32,
                                                     u16* __restrict__ A1) {
  int idx = blockIdx.x * 256 + threadIdx.x;
  if (idx >= RPAIR * KCAT) return;
  // detect int64 storage: odd 32-bit slots all zero (values are small non-negative)
  bool is64 = ((p32[1] | p32[3] | p32[5] | p32[7] | p32[9] | p32[11] | p32[13] | p32[15]) == 0);
  int r = idx / KCAT, c = idx - r * KCAT;
  int b = r >> 7, p = r & 127;
  int which = (c >= HID) ? 1 : 0;
  int cc = which ? (c - HID) : c;          // HID=768 is NOT pow2 — no masking!
  int slot = (b * 128 + p) * 2 + which;
  int node = (is64 ? p32[slot * 2] : p32[slot]) + 1;
  float v = nodes[((size_t)(b * 512 + node)) * HID + cc];
  A1[idx] = f2bf(v);
}

// ---------------------------------------------------------------------------
// pe_proj[t][j] = sum_k pos_emb[t][k] * W1[1536+k][j] + b1[j]     (20 x 768)
// ---------------------------------------------------------------------------
__global__ __launch_bounds__(256) void peproj_kernel(const float* __restrict__ pos_emb,
                                                     const float* __restrict__ W1,
                                                     const float* __restrict__ b1,
                                                     float* __restrict__ pep) {
  __shared__ float pe[HID];
  int t = blockIdx.x, tid = threadIdx.x;
  for (int i = tid; i < HID; i += 256) pe[i] = pos_emb[t * HID + i];
  __syncthreads();
  float acc0 = 0.f, acc1 = 0.f, acc2 = 0.f;
  const float* Wp = W1 + (size_t)KCAT * HID;
  for (int k = 0; k < HID; k++) {
    float p = pe[k];
    const float* wr = Wp + (size_t)k * HID;
    acc0 = fmaf(p, wr[tid], acc0);
    acc1 = fmaf(p, wr[tid + 256], acc1);
    acc2 = fmaf(p, wr[tid + 512], acc2);
  }
  pep[t * HID + tid]       = acc0 + b1[tid];
  pep[t * HID + tid + 256] = acc1 + b1[tid + 256];
  pep[t * HID + tid + 512] = acc2 + b1[tid + 512];
}

// ---------------------------------------------------------------------------
// bf16 MFMA GEMM, A[M][K] bf16 row-major, Bt[n][K] bf16 (B transposed).
// 128x128 tile, BK=32, 4 waves, each wave 64x64 (4x4 frags of 16x16x32).
// EPI 0: C f32 plain   EPI 1: C bf16 = bf16(gelu(acc+bias))   EPI 2: C f32 = acc+bias, col<N guard
// ---------------------------------------------------------------------------
template <int EPI>
__global__ __launch_bounds__(256) void gemm_bt(const u16* __restrict__ A,
                                               const u16* __restrict__ Bt,
                                               const float* __restrict__ bias,
                                               float* __restrict__ Cf,
                                               u16* __restrict__ Cb,
                                               int N, int K) {
  __shared__ __align__(16) u16 As[128 * 32];
  __shared__ __align__(16) u16 Bs[128 * 32];
  const int tid  = threadIdx.x;
  const int lane = tid & 63;
  const int w    = tid >> 6;      // 0..3
  const int wr   = w >> 1, wc = w & 1;
  const int m0 = blockIdx.y * 128;
  const int n0 = blockIdx.x * 128;

  f32x4 acc[4][4];
  const f32x4 fzero = {0.f, 0.f, 0.f, 0.f};
#pragma unroll
  for (int m = 0; m < 4; m++)
#pragma unroll
    for (int n = 0; n < 4; n++) acc[m][n] = fzero;

  const int srow = lane >> 2;          // 0..15
  const int scol = (lane & 3) * 8;     // 0,8,16,24
  const int nkt = K >> 5;

  for (int kt = 0; kt < nkt; ++kt) {
    const int k0 = kt << 5;
    // stage A and B tiles: each wave covers 32 rows of each, 2 instrs apiece
#pragma unroll
    for (int j = 0; j < 2; j++) {
      int rbase = w * 32 + j * 16;
      async16(&As[rbase * 32], A + (size_t)(m0 + rbase + srow) * K + k0 + scol);
      async16(&Bs[rbase * 32], Bt + (size_t)(n0 + rbase + srow) * K + k0 + scol);
    }
    asm volatile("s_waitcnt vmcnt(0)" ::: "memory");
    __syncthreads();

    bf16x8 a[4], b[4];
    const int kk = (lane >> 4) * 8;
#pragma unroll
    for (int m = 0; m < 4; m++)
      a[m] = *reinterpret_cast<const bf16x8*>(&As[(wr * 64 + m * 16 + (lane & 15)) * 32 + kk]);
#pragma unroll
    for (int n = 0; n < 4; n++)
      b[n] = *reinterpret_cast<const bf16x8*>(&Bs[(wc * 64 + n * 16 + (lane & 15)) * 32 + kk]);
#pragma unroll
    for (int m = 0; m < 4; m++)
#pragma unroll
      for (int n = 0; n < 4; n++)
        acc[m][n] = __builtin_amdgcn_mfma_f32_16x16x32_bf16(a[m], b[n], acc[m][n], 0, 0, 0);
    __syncthreads();
  }

  // epilogue: D layout col = lane&15, row = (lane>>4)*4 + j
  const int rr = (lane >> 4) * 4;
  const int cc = lane & 15;
#pragma unroll
  for (int m = 0; m < 4; m++) {
#pragma unroll
    for (int n = 0; n < 4; n++) {
      int col = n0 + wc * 64 + n * 16 + cc;
#pragma unroll
      for (int j = 0; j < 4; j++) {
        int row = m0 + wr * 64 + m * 16 + rr + j;
        float v = acc[m][n][j];
        if (EPI == 0) {
          Cf[(size_t)row * N + col] = v;
        } else if (EPI == 1) {
          v = gelu_tanh(v + bias[col]);
          Cb[(size_t)row * N + col] = f2bf(v);
        } else {
          if (col < N) Cf[(size_t)row * N + col] = v + bias[col];
        }
      }
    }
  }
}

// ---------------------------------------------------------------------------
// fuse1: h1[g] = bf16( LN( gelu( s[r] + pep[t] ) ) * g1 + be1 ),  g = r*20+t
// ---------------------------------------------------------------------------
__global__ __launch_bounds__(256) void fuse1_kernel(const float* __restrict__ s,
                                                    const float* __restrict__ pep,
                                                    const float* __restrict__ g1,
                                                    const float* __restrict__ be1,
                                                    u16* __restrict__ h1) {
  __shared__ float red[8];
  int g = blockIdx.x, tid = threadIdx.x;
  int r = g / TGT, t = g - r * TGT;
  const float* sr = s + (size_t)r * HID;
  const float* pt = pep + (size_t)t * HID;
  float y[3], s1 = 0.f, s2 = 0.f;
#pragma unroll
  for (int i = 0; i < 3; i++) {
    int j = tid + i * 256;
    float x = sr[j] + pt[j];
    y[i] = gelu_tanh(x);
    s1 += y[i];
    s2 += y[i] * y[i];
  }
#pragma unroll
  for (int off = 32; off > 0; off >>= 1) {
    s1 += __shfl_down(s1, off);
    s2 += __shfl_down(s2, off);
  }
  if ((tid & 63) == 0) { red[tid >> 6] = s1; red[4 + (tid >> 6)] = s2; }
  __syncthreads();
  float mean = (red[0] + red[1] + red[2] + red[3]) * (1.0f / HID);
  float var  = (red[4] + red[5] + red[6] + red[7]) * (1.0f / HID) - mean * mean;
  float inv  = rsqrtf(var + 1e-5f);
#pragma unroll
  for (int i = 0; i < 3; i++) {
    int j = tid + i * 256;
    h1[(size_t)g * HID + j] = f2bf((y[i] - mean) * inv * g1[j] + be1[j]);
  }
}

// ---------------------------------------------------------------------------
// fuse2: h2[g] = bf16( LN( G[g] ) * g2 + be2 )      (G already gelu'ed, bf16)
// ---------------------------------------------------------------------------
__global__ __launch_bounds__(256) void fuse2_kernel(const u16* __restrict__ G,
                                                    const float* __restrict__ g2,
                                                    const float* __restrict__ be2,
                                                    u16* __restrict__ h2) {
  __shared__ float red[8];
  int g = blockIdx.x, tid = threadIdx.x;
  const u16* gr = G + (size_t)g * HID;
  float y[3], s1 = 0.f, s2 = 0.f;
#pragma unroll
  for (int i = 0; i < 3; i++) {
    int j = tid + i * 256;
    y[i] = bf2f(gr[j]);
    s1 += y[i];
    s2 += y[i] * y[i];
  }
#pragma unroll
  for (int off = 32; off > 0; off >>= 1) {
    s1 += __shfl_down(s1, off);
    s2 += __shfl_down(s2, off);
  }
  if ((tid & 63) == 0) { red[tid >> 6] = s1; red[4 + (tid >> 6)] = s2; }
  __syncthreads();
  float mean = (red[0] + red[1] + red[2] + red[3]) * (1.0f / HID);
  float var  = (red[4] + red[5] + red[6] + red[7]) * (1.0f / HID) - mean * mean;
  float inv  = rsqrtf(var + 1e-5f);
#pragma unroll
  for (int i = 0; i < 3; i++) {
    int j = tid + i * 256;
    h2[(size_t)g * HID + j] = f2bf((y[i] - mean) * inv * g2[j] + be2[j]);
  }
}

// ---------------------------------------------------------------------------
extern "C" void kernel_launch(void* const* d_in, const int* in_sizes, int n_in,
                              void* d_out, int out_size, void* d_ws, size_t ws_size,
                              hipStream_t stream) {
  const float* input_nodes = (const float*)d_in[0];
  const int*   pairs       = (const int*)d_in[1];
  const float* pos_emb     = (const float*)d_in[2];
  const float* W1  = (const float*)d_in[3];
  const float* b1  = (const float*)d_in[4];
  const float* g1  = (const float*)d_in[5];
  const float* be1 = (const float*)d_in[6];
  const float* W2  = (const float*)d_in[7];
  const float* b2  = (const float*)d_in[8];
  const float* g2  = (const float*)d_in[9];
  const float* be2 = (const float*)d_in[10];
  const float* Wd  = (const float*)d_in[11];
  const float* bd  = (const float*)d_in[12];
  float* out = (float*)d_out;

  char* ws = (char*)d_ws;
  u16*   WdT   = (u16*)(ws + 0);                 // 30592*768*2 = 46,989,312
  u16*   W2T   = (u16*)(ws + 46989312);          // 1,179,648
  u16*   W1lrT = (u16*)(ws + 48168960);          // 2,359,296
  u16*   A1    = (u16*)(ws + 50528256);          // 1,572,864
  float* pep   = (float*)(ws + 52101120);        // 61,440
  float* sbuf  = (float*)(ws + 52162560);        // 1,572,864
  u16*   h1    = (u16*)(ws + 53735424);          // 15,728,640
  u16*   G     = (u16*)(ws + 69464064);          // 15,728,640
  u16*   h2    = (u16*)(ws + 85192704);          // 15,728,640  -> end 100,921,344

  // weight prep (bf16, B^T layouts)
  tconv_kernel<<<dim3(956, 24), 256, 0, stream>>>(Wd, WdT, HID, LBL, NPAD);
  tconv_kernel<<<dim3(24, 24), 256, 0, stream>>>(W2, W2T, HID, HID, HID);
  tconv_kernel<<<dim3(24, 48), 256, 0, stream>>>(W1, W1lrT, KCAT, HID, HID);
  gather_kernel<<<dim3((RPAIR * KCAT + 255) / 256), 256, 0, stream>>>(input_nodes, pairs, A1);
  peproj_kernel<<<dim3(TGT), 256, 0, stream>>>(pos_emb, W1, b1, pep);

  // layer 1: s = [lh|rh] @ W1[0:1536]   (512 x 768)
  gemm_bt<0><<<dim3(6, 4), 256, 0, stream>>>(A1, W1lrT, nullptr, sbuf, nullptr, HID, KCAT);
  fuse1_kernel<<<dim3(ROWS), 256, 0, stream>>>(sbuf, pep, g1, be1, h1);

  // layer 2: G = gelu(h1 @ W2 + b2); h2 = LN(G)
  gemm_bt<1><<<dim3(6, 80), 256, 0, stream>>>(h1, W2T, b2, nullptr, G, HID, HID);
  fuse2_kernel<<<dim3(ROWS), 256, 0, stream>>>(G, g2, be2, h2);

  // head: out = h2 @ Wd + bd   (10240 x 30522)
  gemm_bt<2><<<dim3(239, 80), 256, 0, stream>>>(h2, WdT, bd, out, nullptr, LBL, HID);
}